// Round 11
// baseline (378.463 us; speedup 1.0000x reference)
//
#include <hip/hip_runtime.h>
#include <math.h>
#include <stdint.h>

#define S_LEN 2048
#define DMODEL 512
#define NHEAD 8
#define BATCH 4
#define M_ROWS (BATCH * S_LEN)   // 8192
#define UAC 4194304              // M_ROWS * DMODEL (elements per activation unit)

typedef __attribute__((ext_vector_type(8))) short frag8;   // 8 bf16 (4 VGPRs)
typedef __attribute__((ext_vector_type(4))) float f32x4;   // MFMA accumulator

__device__ inline unsigned short f2bf(float f) {
    unsigned int u = __float_as_uint(f);
    return (unsigned short)((u + 0x7FFFu + ((u >> 16) & 1u)) >> 16);  // RNE
}
__device__ inline float bf2f(unsigned short h) {
    return __uint_as_float(((unsigned int)h) << 16);
}

#if __has_builtin(__builtin_amdgcn_exp2f)
#define EXP2(x) __builtin_amdgcn_exp2f(x)
#else
#define EXP2(x) __expf(0.6931471805599453f * (x))
#endif

// async global->LDS, 16B/lane; lds dest = base + lane*16 (wave-uniform base).
#if __has_builtin(__builtin_amdgcn_global_load_lds)
__device__ __forceinline__ void glds16(const void* g, void* l, int lane) {
    __builtin_amdgcn_global_load_lds(
        (__attribute__((address_space(1))) void*)(uintptr_t)g,
        (__attribute__((address_space(3))) void*)(uintptr_t)l, 16, 0, 0);
    (void)lane;
}
#else
__device__ __forceinline__ void glds16(const void* g, void* l, int lane) {
    ((uint4*)l)[lane] = ((const uint4*)g)[0];
}
#endif

// ---------------------------------------------------------------------------
// Fused weight transpose+cast: 12 segments, one launch. W(K,N) f32 -> Wt(N,K) bf16.
// ---------------------------------------------------------------------------
struct WSeg { const float* src; unsigned short* dst; int K; int N; int start; };
struct WTab { WSeg s[12]; };

__global__ __launch_bounds__(256) void wcast_all(WTab tab)
{
    __shared__ float t[32][33];
    const int bid = blockIdx.x;
    int si = 0;
#pragma unroll
    for (int i = 1; i < 12; ++i) if (bid >= tab.s[i].start) si = i;
    const WSeg sg = tab.s[si];
    const int tile = bid - sg.start;
    const int nk = sg.K >> 5;
    const int k0 = (tile % nk) * 32, n0 = (tile / nk) * 32;
    {
        int kk = threadIdx.x >> 3, nq = (threadIdx.x & 7) * 4;
        float4 v = *(const float4*)&sg.src[(size_t)(k0 + kk) * sg.N + n0 + nq];
        t[kk][nq + 0] = v.x; t[kk][nq + 1] = v.y; t[kk][nq + 2] = v.z; t[kk][nq + 3] = v.w;
    }
    __syncthreads();
    {
        int n = threadIdx.x >> 3, kq = (threadIdx.x & 7) * 4;
        ushort4 o;
        o.x = f2bf(t[kq + 0][n]); o.y = f2bf(t[kq + 1][n]);
        o.z = f2bf(t[kq + 2][n]); o.w = f2bf(t[kq + 3][n]);
        *(ushort4*)&sg.dst[(size_t)(n0 + n) * sg.K + k0 + kq] = o;
    }
}

// x (f32, M x 256) -> bf16
__global__ __launch_bounds__(256) void castx_kernel(
    const float* __restrict__ x, unsigned short* __restrict__ xb)
{
    const size_t i = ((size_t)blockIdx.x * 256 + threadIdx.x) * 8;
    float4 a = *(const float4*)&x[i], b = *(const float4*)&x[i + 4];
    unsigned short us[8];
    us[0] = f2bf(a.x); us[1] = f2bf(a.y); us[2] = f2bf(a.z); us[3] = f2bf(a.w);
    us[4] = f2bf(b.x); us[5] = f2bf(b.y); us[6] = f2bf(b.z); us[7] = f2bf(b.w);
    *(uint4*)&xb[i] = *(uint4*)us;
}

// ---------------------------------------------------------------------------
// Dual V transpose: z=0: Vl->VTl, z=1: Vg->VTg.  (B,S,512) -> (B*H,64,S).
// ---------------------------------------------------------------------------
__global__ __launch_bounds__(256) void vtrans2_kernel(
    const unsigned short* __restrict__ Vl, const unsigned short* __restrict__ Vg,
    unsigned short* __restrict__ VTl, unsigned short* __restrict__ VTg)
{
    __shared__ unsigned short T[64][72];
    const unsigned short* V = blockIdx.z ? Vg : Vl;
    unsigned short* Vt = blockIdx.z ? VTg : VTl;
    const int st = blockIdx.x, bh = blockIdx.y;
    const int b = bh >> 3, h = bh & 7;
    const int tid = threadIdx.x;
    {
        const int s = tid >> 2, d0 = (tid & 3) * 16;
        const unsigned short* src = V + ((size_t)(b * S_LEN + st * 64 + s) * DMODEL + h * 64 + d0);
        *(uint4*)&T[s][d0] = *(const uint4*)src;
        *(uint4*)&T[s][d0 + 8] = *(const uint4*)(src + 8);
    }
    __syncthreads();
    {
        const int d = tid >> 2, s0 = (tid & 3) * 16;
        unsigned short buf[16];
#pragma unroll
        for (int j = 0; j < 16; ++j) buf[j] = T[s0 + j][d];
        unsigned short* dst = Vt + ((size_t)(bh * 64 + d) * S_LEN + st * 64 + s0);
        *(uint4*)&dst[0] = *(const uint4*)&buf[0];
        *(uint4*)&dst[8] = *(const uint4*)&buf[8];
    }
}

// ---------------------------------------------------------------------------
// MFMA GEMM, global_load_lds staging, unpadded LDS + chunk-rotation swizzle.
// Templated on BN (64 or 128). BM=128, BK=64, 256 thr = 4 waves.
// Modes: 0 bias | 1 bias+pos | 2 relu | 3 gate blend (K=1024) |
//        5 merged QKV x2 paths (N=3072) | 6 dual Wo (blockIdx.z selects set)
// ---------------------------------------------------------------------------
template <int MODE, int BN>
__global__ __launch_bounds__(256) void gemm_mfma(
    const unsigned short* __restrict__ A, const unsigned short* __restrict__ A2,
    const unsigned short* __restrict__ Wt, const float* __restrict__ bias,
    const float* __restrict__ bias2, const float* __restrict__ pos,
    unsigned short* __restrict__ C, unsigned short* __restrict__ C2,
    int M, int N, int K)
{
    constexpr int UN = BN / 32;              // u-tiles per wave: 2 or 4
    __shared__ unsigned short As[128 * 64];
    __shared__ unsigned short Bs[BN * 64];
    const int tid = threadIdx.x;
    const int wave = tid >> 6, lane = tid & 63;
    const int lr = lane & 15, quad = lane >> 4;
    const int bm = blockIdx.x * 128, bn = blockIdx.y * BN;
    const int rm = (wave >> 1) * 64, rn = (wave & 1) * (BN / 2);
    const int Khalf = K >> 1;
    const int KA = (MODE == 3) ? Khalf : K;

    // dual-Wo path selection (block-uniform)
    const unsigned short* SA = A;
    const unsigned short* SW = Wt;
    const float* SBIAS = bias;
    unsigned short* SC = C;
    if constexpr (MODE == 6) {
        if (blockIdx.z) { SA = A2; SW = Wt + 512 * 512; SBIAS = bias2; SC = C2; }
    }

    // DMA lane geometry: 8 lanes/row, chunk rotated by row (conflict-free both ways)
    const int lrow = lane >> 3;
    const int gch = ((lane & 7) - lrow) & 7;
    const size_t laneA = (size_t)(bm + wave * 32 + lrow) * KA + gch * 8;
    const size_t laneB = (size_t)(bn + wave * (BN / 4) + lrow) * K + gch * 8;
    unsigned short* ldsA = As + wave * 2048;
    unsigned short* ldsB = Bs + wave * (BN * 16);

    f32x4 acc[4][UN];
#pragma unroll
    for (int t = 0; t < 4; ++t)
#pragma unroll
        for (int u = 0; u < UN; ++u) acc[t][u] = (f32x4){0.f, 0.f, 0.f, 0.f};

    const int sw0 = ((quad + lr) & 7) * 8;
    const int sw1 = ((quad + lr + 4) & 7) * 8;

    for (int k0 = 0; k0 < K; k0 += 64) {
        __syncthreads();                      // prev iteration's frag reads done
        const unsigned short* Ab; int kadj;
        if constexpr (MODE == 3) { Ab = (k0 < Khalf) ? A : A2; kadj = k0 & (Khalf - 1); }
        else { Ab = SA; kadj = k0; }
        const unsigned short* pa = Ab + laneA + kadj;
        glds16(pa,           ldsA,        lane);
        glds16(pa + 8 * KA,  ldsA + 512,  lane);
        glds16(pa + 16 * KA, ldsA + 1024, lane);
        glds16(pa + 24 * KA, ldsA + 1536, lane);
        const unsigned short* pb = SW + laneB + k0;
#pragma unroll
        for (int i = 0; i < UN; ++i)
            glds16(pb + i * 8 * K, ldsB + i * 512, lane);
        __syncthreads();                      // vmcnt(0) drain before reads

#pragma unroll
        for (int kc = 0; kc < 2; ++kc) {
            const int sw = kc ? sw1 : sw0;
            frag8 af[4], bf[UN];
#pragma unroll
            for (int t = 0; t < 4; ++t)
                af[t] = *(const frag8*)&As[(rm + t * 16 + lr) * 64 + sw];
#pragma unroll
            for (int u = 0; u < UN; ++u)
                bf[u] = *(const frag8*)&Bs[(rn + u * 16 + lr) * 64 + sw];
#pragma unroll
            for (int t = 0; t < 4; ++t)
#pragma unroll
                for (int u = 0; u < UN; ++u)
                    acc[t][u] = __builtin_amdgcn_mfma_f32_16x16x32_bf16(
                        af[t], bf[u], acc[t][u], 0, 0, 0);
        }
    }

    // ---- epilogue ----
#pragma unroll
    for (int t = 0; t < 4; ++t) {
#pragma unroll
        for (int i = 0; i < 4; ++i) {
            const int m = bm + rm + t * 16 + quad * 4 + i;
#pragma unroll
            for (int u = 0; u < UN; ++u) {
                const int n = bn + rn + u * 16 + lr;
                if constexpr (MODE == 5) {
                    const int mat = n >> 9;
                    const int nn = n & 511;
                    const float* bp = (mat < 3) ? (bias + (mat << 9))
                                                : (bias2 + ((mat - 3) << 9));
                    float v = acc[t][u][i] + bp[nn];
                    if (mat == 0 || mat == 3) v *= 0.18033688011112042f;  // 0.125*log2e
                    C[(size_t)mat * UAC + (size_t)m * DMODEL + nn] = f2bf(v);
                } else {
                    float v = acc[t][u][i] + SBIAS[n];
                    if constexpr (MODE == 1) v += pos[(size_t)(m & (S_LEN - 1)) * N + n];
                    if constexpr (MODE == 2) v = fmaxf(v, 0.0f);
                    if constexpr (MODE == 3) {
                        float g = tanhf(fmaxf(v, 0.0f));
                        float lo = bf2f(A[(size_t)m * Khalf + n]);
                        float go = bf2f(A2[(size_t)m * Khalf + n]);
                        v = g * lo + (1.0f - g) * go;
                    }
                    SC[(size_t)m * N + n] = f2bf(v);
                }
            }
        }
    }
}

// ---------------------------------------------------------------------------
// LOCAL banded attention: 64-row Q-tiles, single-buffer 2-barrier loop
// (R8 best variant; only 3 K-tiles per block, 24 KB LDS -> 6 blocks/CU).
// ---------------------------------------------------------------------------
__global__ __launch_bounds__(256) void attn_local(
    const unsigned short* __restrict__ Q, const unsigned short* __restrict__ Kv,
    const unsigned short* __restrict__ Vt, unsigned short* __restrict__ O)
{
    __shared__ unsigned short Ks[64 * 64];
    __shared__ unsigned short Vts[64 * 64];
    __shared__ unsigned short Ps[64 * 64];
    const int qt = blockIdx.x, h = blockIdx.y, b = blockIdx.z;
    const int tid = threadIdx.x;
    const int wave = tid >> 6, lane = tid & 63;
    const int lr = lane & 15, quad = lane >> 4;

    {
        const int q = tid >> 2, c8 = (tid & 3) * 2;
        const unsigned short* src = Q + ((size_t)(b * S_LEN + qt * 64 + q) * DMODEL + h * 64 + c8 * 8);
        *(uint4*)&Ps[q * 64 + (((c8 + q) & 7) * 8)] = *(const uint4*)src;
        *(uint4*)&Ps[q * 64 + (((c8 + 1 + q) & 7) * 8)] = *(const uint4*)(src + 8);
    }
    const int sw0 = ((quad + lr) & 7) * 8;
    const int sw1 = ((quad + lr + 4) & 7) * 8;
    const int prow = (wave * 16 + lr) * 64;
    frag8 qf[2];
    qf[0] = *(const frag8*)&Ps[prow + sw0];
    qf[1] = *(const frag8*)&Ps[prow + sw1];

    f32x4 oacc[4];
#pragma unroll
    for (int t = 0; t < 4; ++t) oacc[t] = (f32x4){0.f, 0.f, 0.f, 0.f};
    float l_r = 0.f;

    const int kt0 = qt > 0 ? qt - 1 : 0;
    const int kt1 = qt < 31 ? qt + 1 : 31;

    const int lrow = lane >> 3;
    const int gch = ((lane & 7) - lrow) & 7;
    const unsigned short* kp = Kv + ((size_t)(b * S_LEN + kt0 * 64 + wave * 16 + lrow) * DMODEL + h * 64 + gch * 8);
    const unsigned short* vp = Vt + ((size_t)((b * 8 + h) * 64 + wave * 16 + lrow) * S_LEN + kt0 * 64 + gch * 8);
    unsigned short* lk = Ks + wave * 1024;
    unsigned short* lv = Vts + wave * 1024;

    for (int kt = kt0; kt <= kt1; ++kt) {
        __syncthreads();
        glds16(kp, lk, lane);
        glds16(kp + 8 * DMODEL, lk + 512, lane);
        glds16(vp, lv, lane);
        glds16(vp + 8 * S_LEN, lv + 512, lane);
        kp += 64 * DMODEL; vp += 64;
        __syncthreads();

        f32x4 sacc[4];
#pragma unroll
        for (int t = 0; t < 4; ++t) sacc[t] = (f32x4){0.f, 0.f, 0.f, 0.f};
#pragma unroll
        for (int kc = 0; kc < 2; ++kc) {
            const int sw = kc ? sw1 : sw0;
#pragma unroll
            for (int t = 0; t < 4; ++t) {
                frag8 kf = *(const frag8*)&Ks[(t * 16 + lr) * 64 + sw];
                sacc[t] = __builtin_amdgcn_mfma_f32_16x16x32_bf16(kf, qf[kc], sacc[t], 0, 0, 0);
            }
        }

#pragma unroll
        for (int t = 0; t < 4; ++t) {
            float p0 = EXP2(sacc[t][0]);
            float p1 = EXP2(sacc[t][1]);
            float p2 = EXP2(sacc[t][2]);
            float p3 = EXP2(sacc[t][3]);
            const int qa = qt * 64 + wave * 16 + lr;
            const int ca = kt * 64 + t * 16 + quad * 4;
            int d0 = qa - ca;
            if (d0 > 32 || d0 < -32) p0 = 0.f;
            int d1 = qa - (ca + 1);
            if (d1 > 32 || d1 < -32) p1 = 0.f;
            int d2 = qa - (ca + 2);
            if (d2 > 32 || d2 < -32) p2 = 0.f;
            int d3 = qa - (ca + 3);
            if (d3 > 32 || d3 < -32) p3 = 0.f;
            const unsigned u0 = __float_as_uint(p0) & 0xFFFF0000u;
            const unsigned u1 = __float_as_uint(p1) & 0xFFFF0000u;
            const unsigned u2 = __float_as_uint(p2) & 0xFFFF0000u;
            const unsigned u3 = __float_as_uint(p3) & 0xFFFF0000u;
            l_r += (__uint_as_float(u0) + __uint_as_float(u1)) +
                   (__uint_as_float(u2) + __uint_as_float(u3));
            uint2 pw;
            pw.x = __builtin_amdgcn_perm(u1, u0, 0x07060302);
            pw.y = __builtin_amdgcn_perm(u3, u2, 0x07060302);
            const int slot = ((2 * t + (quad >> 1) + lr) & 7) * 8 + (quad & 1) * 4;
            *(uint2*)&Ps[prow + slot] = pw;
        }

#pragma unroll
        for (int cc = 0; cc < 2; ++cc) {
            const int sw = cc ? sw1 : sw0;
            frag8 pa = *(const frag8*)&Ps[prow + sw];
#pragma unroll
            for (int t = 0; t < 4; ++t) {
                frag8 vf = *(const frag8*)&Vts[(t * 16 + lr) * 64 + sw];
                oacc[t] = __builtin_amdgcn_mfma_f32_16x16x32_bf16(pa, vf, oacc[t], 0, 0, 0);
            }
        }
    }

    l_r += __shfl_xor(l_r, 16);
    l_r += __shfl_xor(l_r, 32);
#pragma unroll
    for (int i = 0; i < 4; ++i) {
        const float inv = 1.0f / __shfl(l_r, quad * 4 + i);
        const int q = qt * 64 + wave * 16 + quad * 4 + i;
#pragma unroll
        for (int t = 0; t < 4; ++t)
            O[(size_t)(b * S_LEN + q) * DMODEL + h * 64 + t * 16 + lr] = f2bf(oacc[t][i] * inv);
    }
}

// ---------------------------------------------------------------------------
// GLOBAL attention: 128-row Q-tiles (32 q/wave, 2 stripes), K/V DOUBLE-BUFFER
// with ONE barrier per iter — the barrier drains the prefetch issued a full
// compute section earlier, hiding the ~900-cyc load latency that binds at the
// grid-limited 2 blocks/CU. LDS: Ks 2x8K + Vts 2x8K + Ps 16K = 48 KB (3/CU cap,
// grid gives 2 -> dbuf costs no occupancy). No mask. Max-free exp2 softmax.
// ---------------------------------------------------------------------------
#define ISSUE_KV_G(KT, BUF) do {                                                \
    const unsigned short* _kp = kbase + (size_t)(KT) * (64 * DMODEL);           \
    const unsigned short* _vp = vbase + (size_t)(KT) * 64;                      \
    unsigned short* _lk = Ks + (BUF) * 4096 + wave * 1024;                      \
    unsigned short* _lv = Vts + (BUF) * 4096 + wave * 1024;                     \
    glds16(_kp, _lk, lane); glds16(_kp + 8 * DMODEL, _lk + 512, lane);          \
    glds16(_vp, _lv, lane); glds16(_vp + 8 * S_LEN, _lv + 512, lane);           \
} while (0)

__global__ __launch_bounds__(256) void attn_global(
    const unsigned short* __restrict__ Q, const unsigned short* __restrict__ Kv,
    const unsigned short* __restrict__ Vt, unsigned short* __restrict__ O)
{
    __shared__ unsigned short Ks[2 * 64 * 64];
    __shared__ unsigned short Vts[2 * 64 * 64];
    __shared__ unsigned short Ps[128 * 64];
    const int qt = blockIdx.x, h = blockIdx.y, b = blockIdx.z;
    const int tid = threadIdx.x;
    const int wave = tid >> 6, lane = tid & 63;
    const int lr = lane & 15, quad = lane >> 4;

    // stage Q (128 rows; wave w covers rows [32w,32w+32) -> wave-private)
    {
        const int q = tid >> 1, cb = (tid & 1) * 4;
        const unsigned short* src = Q + ((size_t)(b * S_LEN + qt * 128 + q) * DMODEL + h * 64 + cb * 8);
#pragma unroll
        for (int i = 0; i < 4; ++i)
            *(uint4*)&Ps[q * 64 + (((cb + i + q) & 7) * 8)] = *(const uint4*)(src + i * 8);
    }
    const int sw0 = ((quad + lr) & 7) * 8;
    const int sw1 = ((quad + lr + 4) & 7) * 8;
    const int ws32 = wave * 32;
    frag8 qf[2][2];
#pragma unroll
    for (int s = 0; s < 2; ++s) {
        qf[s][0] = *(const frag8*)&Ps[(ws32 + s * 16 + lr) * 64 + sw0];
        qf[s][1] = *(const frag8*)&Ps[(ws32 + s * 16 + lr) * 64 + sw1];
    }

    f32x4 oacc[2][4];
#pragma unroll
    for (int s = 0; s < 2; ++s)
#pragma unroll
        for (int t = 0; t < 4; ++t) oacc[s][t] = (f32x4){0.f, 0.f, 0.f, 0.f};
    float l_r[2] = {0.f, 0.f};

    // glds lane geometry
    const int lrow = lane >> 3;
    const int gch = ((lane & 7) - lrow) & 7;
    const unsigned short* kbase = Kv + ((size_t)(b * S_LEN + wave * 16 + lrow) * DMODEL + h * 64 + gch * 8);
    const unsigned short* vbase = Vt + ((size_t)((b * 8 + h) * 64 + wave * 16 + lrow) * S_LEN + gch * 8);

    ISSUE_KV_G(0, 0);

    for (int it = 0; it < 32; ++it) {
        const int buf = it & 1;
        __syncthreads();                 // drains glds for current buf (issued a full iter ago)
        if (it + 1 < 32) ISSUE_KV_G(it + 1, buf ^ 1);
        const unsigned short* kb = Ks + buf * 4096;
        const unsigned short* vb = Vts + buf * 4096;

        // ---- S^T = K Q^T per stripe ----
        f32x4 sacc[2][4];
#pragma unroll
        for (int s = 0; s < 2; ++s)
#pragma unroll
            for (int t = 0; t < 4; ++t) sacc[s][t] = (f32x4){0.f, 0.f, 0.f, 0.f};
#pragma unroll
        for (int kc = 0; kc < 2; ++kc) {
            const int sw = kc ? sw1 : sw0;
#pragma unroll
            for (int t = 0; t < 4; ++t) {
                frag8 kf = *(const frag8*)&kb[(t * 16 + lr) * 64 + sw];
                sacc[0][t] = __builtin_amdgcn_mfma_f32_16x16x32_bf16(kf, qf[0][kc], sacc[0][t], 0, 0, 0);
                sacc[1][t] = __builtin_amdgcn_mfma_f32_16x16x32_bf16(kf, qf[1][kc], sacc[1][t], 0, 0, 0);
            }
        }

        // ---- softmax: p = 2^s; truncate-pack; P -> Ps ----
#pragma unroll
        for (int s = 0; s < 2; ++s) {
            const int prow = (ws32 + s * 16 + lr) * 64;
#pragma unroll
            for (int t = 0; t < 4; ++t) {
                const unsigned u0 = __float_as_uint(EXP2(sacc[s][t][0])) & 0xFFFF0000u;
                const unsigned u1 = __float_as_uint(EXP2(sacc[s][t][1])) & 0xFFFF0000u;
                const unsigned u2 = __float_as_uint(EXP2(sacc[s][t][2])) & 0xFFFF0000u;
                const unsigned u3 = __float_as_uint(EXP2(sacc[s][t][3])) & 0xFFFF0000u;
                l_r[s] += (__uint_as_float(u0) + __uint_as_float(u1)) +
                          (__uint_as_float(u2) + __uint_as_float(u3));
                uint2 pw;
                pw.x = __builtin_amdgcn_perm(u1, u0, 0x07060302);
                pw.y = __builtin_amdgcn_perm(u3, u2, 0x07060302);
                const int slot = ((2 * t + (quad >> 1) + lr) & 7) * 8 + (quad & 1) * 4;
                *(uint2*)&Ps[prow + slot] = pw;
            }
        }
        // no barrier: Ps rows [32w,32w+32) are wave-private

        // ---- O += P V per stripe ----
#pragma unroll
        for (int cc = 0; cc < 2; ++cc) {
            const int sw = cc ? sw1 : sw0;
            frag8 pa0 = *(const frag8*)&Ps[(ws32 + lr) * 64 + sw];
            frag8 pa1 = *(const frag8*)&Ps[(ws32 + 16 + lr) * 64 + sw];
#pragma unroll
            for (int t = 0; t < 4; ++t) {
                frag8 vf = *(const frag8*)&vb[(t * 16 + lr) * 64 + sw];
                oacc[0][t] = __builtin_amdgcn_mfma_f32_16x16x32_bf16(pa0, vf, oacc[0][t], 0, 0, 0);
                oacc[1][t] = __builtin_amdgcn_mfma_f32_16x16x32_bf16(pa1, vf, oacc[1][t], 0, 0, 0);
            }
        }
    }

    // ---- deferred row-sum reduction + epilogue ----
#pragma unroll
    for (int s = 0; s < 2; ++s) {
        float l = l_r[s];
        l += __shfl_xor(l, 16);
        l += __shfl_xor(l, 32);
#pragma unroll
        for (int i = 0; i < 4; ++i) {
            const float inv = 1.0f / __shfl(l, quad * 4 + i);
            const int q = qt * 128 + ws32 + s * 16 + quad * 4 + i;
#pragma unroll
            for (int t = 0; t < 4; ++t)
                O[(size_t)(b * S_LEN + q) * DMODEL + h * 64 + t * 16 + lr] =
                    f2bf(oacc[s][t][i] * inv);
        }
    }
}

// ---------------------------------------------------------------------------
// LayerNorm (bf16 in/out, fp32 math): 256-thr blocks, one wave per row.
// ---------------------------------------------------------------------------
__device__ inline float wave_sum64(float v) {
#pragma unroll
    for (int off = 1; off < 64; off <<= 1) v += __shfl_xor(v, off);
    return v;
}

__global__ __launch_bounds__(256) void ln_res_kernel(
    const unsigned short* __restrict__ A, const unsigned short* __restrict__ Bb,
    const float* __restrict__ g, const float* __restrict__ be,
    unsigned short* __restrict__ out)
{
    const size_t row = blockIdx.x * 4 + (threadIdx.x >> 6);
    const int lane = threadIdx.x & 63;
    float x[8]; float s = 0.f;
#pragma unroll
    for (int k = 0; k < 8; ++k) {
        size_t idx = row * DMODEL + k * 64 + lane;
        x[k] = bf2f(A[idx]) + bf2f(Bb[idx]);
        s += x[k];
    }
    s = wave_sum64(s);
    float mean = s * (1.0f / DMODEL);
    float v = 0.f;
#pragma unroll
    for (int k = 0; k < 8; ++k) { float d = x[k] - mean; v += d * d; }
    v = wave_sum64(v) * (1.0f / DMODEL);
    float r = rsqrtf(v + 1e-5f);
#pragma unroll
    for (int k = 0; k < 8; ++k)
        out[row * DMODEL + k * 64 + lane] =
            f2bf((x[k] - mean) * r * g[k * 64 + lane] + be[k * 64 + lane]);
}

__global__ __launch_bounds__(256) void ln_double_kernel(
    const unsigned short* __restrict__ A, const unsigned short* __restrict__ Bb,
    const float* __restrict__ g2, const float* __restrict__ b2,
    const float* __restrict__ g3, const float* __restrict__ b3,
    unsigned short* __restrict__ out)
{
    const size_t row = blockIdx.x * 4 + (threadIdx.x >> 6);
    const int lane = threadIdx.x & 63;
    float x[8]; float s = 0.f;
#pragma unroll
    for (int k = 0; k < 8; ++k) {
        size_t idx = row * DMODEL + k * 64 + lane;
        x[k] = bf2f(A[idx]) + bf2f(Bb[idx]);
        s += x[k];
    }
    s = wave_sum64(s);
    float mean = s * (1.0f / DMODEL);
    float v = 0.f;
#pragma unroll
    for (int k = 0; k < 8; ++k) { float d = x[k] - mean; v += d * d; }
    v = wave_sum64(v) * (1.0f / DMODEL);
    float r = rsqrtf(v + 1e-5f);
    float t[8]; float s2 = 0.f;
#pragma unroll
    for (int k = 0; k < 8; ++k) {
        t[k] = (x[k] - mean) * r * g2[k * 64 + lane] + b2[k * 64 + lane];
        s2 += t[k];
    }
    s2 = wave_sum64(s2);
    float mean2 = s2 * (1.0f / DMODEL);
    float v2 = 0.f;
#pragma unroll
    for (int k = 0; k < 8; ++k) { float d = t[k] - mean2; v2 += d * d; }
    v2 = wave_sum64(v2) * (1.0f / DMODEL);
    float r2 = rsqrtf(v2 + 1e-5f);
#pragma unroll
    for (int k = 0; k < 8; ++k)
        out[row * DMODEL + k * 64 + lane] =
            f2bf((t[k] - mean2) * r2 * g3[k * 64 + lane] + b3[k * 64 + lane]);
}

// ---------------------------------------------------------------------------
// Mean-pool over S (bf16 in, fp32 atomics) + tiny final GEMM (fp32).
// ---------------------------------------------------------------------------
__global__ __launch_bounds__(256) void pool_kernel(
    const unsigned short* __restrict__ h2, float* __restrict__ pooled)
{
    const int b = blockIdx.x >> 4;
    const int chunk = blockIdx.x & 15;
    const int tid = threadIdx.x;
    float s0 = 0.f, s1 = 0.f;
    size_t base = (size_t)(b * S_LEN + chunk * 128) * DMODEL;
    for (int r = 0; r < 128; ++r) {
        s0 += bf2f(h2[base + (size_t)r * DMODEL + tid]);
        s1 += bf2f(h2[base + (size_t)r * DMODEL + 256 + tid]);
    }
    atomicAdd(&pooled[b * DMODEL + tid], s0);
    atomicAdd(&pooled[b * DMODEL + 256 + tid], s1);
}

__global__ __launch_bounds__(128) void out_kernel(
    const float* __restrict__ pooled, const float* __restrict__ w,
    const float* __restrict__ bias, float* __restrict__ out)
{
    const int b = blockIdx.x;
    const int o = threadIdx.x;
    float acc = 0.f;
    for (int d = 0; d < DMODEL; ++d)
        acc += pooled[b * DMODEL + d] * w[d * 128 + o];
    out[b * 128 + o] = acc * (1.0f / S_LEN) + bias[o];
}

// ---------------------------------------------------------------------------
extern "C" void kernel_launch(void* const* d_in, const int* in_sizes, int n_in,
                              void* d_out, int out_size, void* d_ws, size_t ws_size,
                              hipStream_t stream)
{
    const float* x      = (const float*)d_in[0];
    const float* pos    = (const float*)d_in[1];
    const float* win_w  = (const float*)d_in[2];
    const float* win_b  = (const float*)d_in[3];
    const float* l_wqkv = (const float*)d_in[4];
    const float* l_bqkv = (const float*)d_in[5];
    const float* l_wo   = (const float*)d_in[6];
    const float* l_bo   = (const float*)d_in[7];
    const float* g_wqkv = (const float*)d_in[8];
    const float* g_bqkv = (const float*)d_in[9];
    const float* g_wo   = (const float*)d_in[10];
    const float* g_bo   = (const float*)d_in[11];
    const float* gate_w = (const float*)d_in[12];
    const float* gate_b = (const float*)d_in[13];
    const float* ffn_w1 = (const float*)d_in[14];
    const float* ffn_b1 = (const float*)d_in[15];
    const float* ffn_w2 = (const float*)d_in[16];
    const float* ffn_b2 = (const float*)d_in[17];
    const float* n1_g   = (const float*)d_in[18];
    const float* n1_b   = (const float*)d_in[19];
    const float* n2_g   = (const float*)d_in[20];
    const float* n2_b   = (const float*)d_in[21];
    const float* n3_g   = (const float*)d_in[22];
    const float* n3_b   = (const float*)d_in[23];
    const float* out_w  = (const float*)d_in[24];
    const float* out_b  = (const float*)d_in[25];
    float* out = (float*)d_out;

    unsigned short* ws16 = (unsigned short*)d_ws;
    const size_t UA = (size_t)UAC;
    // units 0..7 (8 MiB each):
    unsigned short* H    = ws16 + 0 * UA;
    unsigned short* QKV  = ws16 + 1 * UA;   // units 1..6: Ql,Kl,Vl,Qg,Kg,Vg
    unsigned short* Ql   = ws16 + 1 * UA;
    unsigned short* Kl   = ws16 + 2 * UA;
    unsigned short* Vl   = ws16 + 3 * UA;
    unsigned short* Qg   = ws16 + 4 * UA;
    unsigned short* Kg   = ws16 + 5 * UA;
    unsigned short* Vg   = ws16 + 6 * UA;
    unsigned short* VTl  = ws16 + 7 * UA;   // transposed V local (B*H,64,S)
    unsigned short* AOl    = Vl;            // Vl dead after vtrans2
    unsigned short* LO     = Kl;            // Kl dead after attn
    unsigned short* GO     = Qg;            // Qg dead after attn
    unsigned short* FUSED  = Kg;            // Kg dead after attn
    unsigned short* H1     = Vg;            // Vg dead after vtrans2
    unsigned short* FFNMID = Vl;            // units 3..4 (AOl, GO dead post-gate)
    unsigned short* FFNOUT = Ql;            // Ql dead after attn
    unsigned short* H2     = Kl;            // LO dead after gate
    float* POOLED = (float*)(void*)H;       // H dead after LN1

    // transposed bf16 weights + pre-cast x
    unsigned short* wt = ws16 + 8 * UA;
    unsigned short* win_t  = wt;                      // 512 x 256
    unsigned short* lqkv_t = win_t  + 131072;         // 3 x (512 x 512)
    unsigned short* gqkv_t = lqkv_t + 786432;         // 3 x (512 x 512)
    unsigned short* lwo_t  = gqkv_t + 786432;
    unsigned short* gwo_t  = lwo_t  + 262144;
    unsigned short* gate_t = gwo_t  + 262144;         // 512 x 1024
    unsigned short* ffn1_t = gate_t + 524288;         // 1024 x 512
    unsigned short* ffn2_t = ffn1_t + 524288;         // 512 x 1024
    unsigned short* xb     = ffn2_t + 524288;         // 8192 x 256 bf16
    // spare region
    unsigned short* VTg    = xb + 2097152;            // 8 MB: transposed V global
    unsigned short* AOg    = VTg + UA;                // 8 MB: global attn out

    WTab tab;
    tab.s[0]  = {win_w,             win_t,             256,  512,    0};
    tab.s[1]  = {l_wqkv + 0*262144, lqkv_t + 0*262144, 512,  512,  128};
    tab.s[2]  = {l_wqkv + 1*262144, lqkv_t + 1*262144, 512,  512,  384};
    tab.s[3]  = {l_wqkv + 2*262144, lqkv_t + 2*262144, 512,  512,  640};
    tab.s[4]  = {g_wqkv + 0*262144, gqkv_t + 0*262144, 512,  512,  896};
    tab.s[5]  = {g_wqkv + 1*262144, gqkv_t + 1*262144, 512,  512, 1152};
    tab.s[6]  = {g_wqkv + 2*262144, gqkv_t + 2*262144, 512,  512, 1408};
    tab.s[7]  = {l_wo,              lwo_t,             512,  512, 1664};
    tab.s[8]  = {g_wo,              gwo_t,             512,  512, 1920};
    tab.s[9]  = {gate_w,            gate_t,            1024, 512, 2176};
    tab.s[10] = {ffn_w1,            ffn1_t,            512, 1024, 2688};
    tab.s[11] = {ffn_w2,            ffn2_t,            1024, 512, 3200};

    dim3 blk(256);
    castx_kernel<<<dim3(1024), blk, 0, stream>>>(x, xb);
    wcast_all<<<dim3(3712), blk, 0, stream>>>(tab);

    dim3 gD(M_ROWS / 128, 512 / 64);        // 64 x 8   (BN=64)
    dim3 gW(M_ROWS / 128, 512 / 64, 2);     // dual Wo
    dim3 gQ(M_ROWS / 128, 3072 / 128);      // 64 x 24  (BN=128, merged QKV x2)
    dim3 gF(M_ROWS / 128, 1024 / 128);      // 64 x 8   (BN=128, FFN1)
    dim3 gAL(S_LEN / 64, NHEAD, BATCH);     // local: 32 x 8 x 4
    dim3 gAG(S_LEN / 128, NHEAD, BATCH);    // global: 16 x 8 x 4
    dim3 gV(S_LEN / 64, BATCH * NHEAD, 2);  // dual vtrans

    // h = x @ win_w + win_b + pos
    gemm_mfma<1, 64><<<gD, blk, 0, stream>>>(xb, nullptr, win_t, win_b, nullptr, pos, H, nullptr, M_ROWS, 512, 256);

    // merged QKV for both paths (Q mats pre-scaled by 0.125*log2e)
    gemm_mfma<5, 128><<<gQ, blk, 0, stream>>>(H, nullptr, lqkv_t, l_bqkv, g_bqkv, nullptr, QKV, nullptr, M_ROWS, 3072, 512);

    // dual V transpose (both paths at once)
    vtrans2_kernel<<<gV, blk, 0, stream>>>(Vl, Vg, VTl, VTg);

    // local (banded) and global attention — separate launches (load balance)
    attn_local<<<gAL, blk, 0, stream>>>(Ql, Kl, VTl, AOl);
    attn_global<<<gAG, blk, 0, stream>>>(Qg, Kg, VTg, AOg);

    // dual Wo: z=0 local (AOl@lwo -> LO), z=1 global (AOg@gwo -> GO)
    gemm_mfma<6, 64><<<gW, blk, 0, stream>>>(AOl, AOg, lwo_t, l_bo, g_bo, nullptr, LO, GO, M_ROWS, 512, 512);

    // gate + fuse
    gemm_mfma<3, 64><<<gD, blk, 0, stream>>>(LO, GO, gate_t, gate_b, nullptr, nullptr, FUSED, nullptr, M_ROWS, 512, 1024);

    // h1 = LN(h + fused)
    ln_res_kernel<<<M_ROWS / 4, blk, 0, stream>>>(H, FUSED, n1_g, n1_b, H1);

    // FFN
    gemm_mfma<2, 128><<<gF, blk, 0, stream>>>(H1, nullptr, ffn1_t, ffn_b1, nullptr, nullptr, FFNMID, nullptr, M_ROWS, 1024, 512);
    gemm_mfma<0, 64><<<gD, blk, 0, stream>>>(FFNMID, nullptr, ffn2_t, ffn_b2, nullptr, nullptr, FFNOUT, nullptr, M_ROWS, 512, 1024);

    // h2 = LN(LN(h1 + ffn, n2), n3)
    ln_double_kernel<<<M_ROWS / 4, blk, 0, stream>>>(H1, FFNOUT, n2_g, n2_b, n3_g, n3_b, H2);

    // pool + final projection
    hipMemsetAsync(POOLED, 0, BATCH * DMODEL * sizeof(float), stream);
    pool_kernel<<<dim3(BATCH * 16), blk, 0, stream>>>(H2, POOLED);
    out_kernel<<<dim3(BATCH), dim3(128), 0, stream>>>(POOLED, out_w, out_b, out);
}

// Round 12
// 345.213 us; speedup vs baseline: 1.0963x; 1.0963x over previous
//
#include <hip/hip_runtime.h>
#include <math.h>
#include <stdint.h>

#define S_LEN 2048
#define DMODEL 512
#define NHEAD 8
#define BATCH 4
#define M_ROWS (BATCH * S_LEN)   // 8192
#define UAC 4194304              // M_ROWS * DMODEL (elements per activation unit)

typedef __attribute__((ext_vector_type(8))) short frag8;   // 8 bf16 (4 VGPRs)
typedef __attribute__((ext_vector_type(4))) float f32x4;   // MFMA accumulator

__device__ inline unsigned short f2bf(float f) {
    unsigned int u = __float_as_uint(f);
    return (unsigned short)((u + 0x7FFFu + ((u >> 16) & 1u)) >> 16);  // RNE
}
__device__ inline float bf2f(unsigned short h) {
    return __uint_as_float(((unsigned int)h) << 16);
}

#if __has_builtin(__builtin_amdgcn_exp2f)
#define EXP2(x) __builtin_amdgcn_exp2f(x)
#else
#define EXP2(x) __expf(0.6931471805599453f * (x))
#endif

// async global->LDS, 16B/lane; lds dest = base + lane*16 (wave-uniform base).
#if __has_builtin(__builtin_amdgcn_global_load_lds)
__device__ __forceinline__ void glds16(const void* g, void* l, int lane) {
    __builtin_amdgcn_global_load_lds(
        (__attribute__((address_space(1))) void*)(uintptr_t)g,
        (__attribute__((address_space(3))) void*)(uintptr_t)l, 16, 0, 0);
    (void)lane;
}
#else
__device__ __forceinline__ void glds16(const void* g, void* l, int lane) {
    ((uint4*)l)[lane] = ((const uint4*)g)[0];
}
#endif

// ---------------------------------------------------------------------------
// Fused weight transpose+cast + x-cast: 13 segments, ONE launch.
// N>0: W(K,N) f32 -> Wt(N,K) bf16 (32x32 tiles). N==0: plain f32->bf16 cast
// (2048 elements per block).
// ---------------------------------------------------------------------------
struct WSeg { const float* src; unsigned short* dst; int K; int N; int start; };
struct WTab { WSeg s[13]; };

__global__ __launch_bounds__(256) void wcast_all(WTab tab)
{
    __shared__ float t[32][33];
    const int bid = blockIdx.x;
    int si = 0;
#pragma unroll
    for (int i = 1; i < 13; ++i) if (bid >= tab.s[i].start) si = i;
    const WSeg sg = tab.s[si];
    const int tile = bid - sg.start;
    if (sg.N == 0) {   // plain cast segment (x -> xb)
        const size_t i = ((size_t)tile * 256 + threadIdx.x) * 8;
        float4 a = *(const float4*)&sg.src[i], b = *(const float4*)&sg.src[i + 4];
        unsigned short us[8];
        us[0] = f2bf(a.x); us[1] = f2bf(a.y); us[2] = f2bf(a.z); us[3] = f2bf(a.w);
        us[4] = f2bf(b.x); us[5] = f2bf(b.y); us[6] = f2bf(b.z); us[7] = f2bf(b.w);
        *(uint4*)&sg.dst[i] = *(uint4*)us;
        return;
    }
    const int nk = sg.K >> 5;
    const int k0 = (tile % nk) * 32, n0 = (tile / nk) * 32;
    {
        int kk = threadIdx.x >> 3, nq = (threadIdx.x & 7) * 4;
        float4 v = *(const float4*)&sg.src[(size_t)(k0 + kk) * sg.N + n0 + nq];
        t[kk][nq + 0] = v.x; t[kk][nq + 1] = v.y; t[kk][nq + 2] = v.z; t[kk][nq + 3] = v.w;
    }
    __syncthreads();
    {
        int n = threadIdx.x >> 3, kq = (threadIdx.x & 7) * 4;
        ushort4 o;
        o.x = f2bf(t[kq + 0][n]); o.y = f2bf(t[kq + 1][n]);
        o.z = f2bf(t[kq + 2][n]); o.w = f2bf(t[kq + 3][n]);
        *(ushort4*)&sg.dst[(size_t)(n0 + n) * sg.K + k0 + kq] = o;
    }
}

// ---------------------------------------------------------------------------
// Dual V transpose: z=0: Vl->VTl, z=1: Vg->VTg.  (B,S,512) -> (B*H,64,S).
// ---------------------------------------------------------------------------
__global__ __launch_bounds__(256) void vtrans2_kernel(
    const unsigned short* __restrict__ Vl, const unsigned short* __restrict__ Vg,
    unsigned short* __restrict__ VTl, unsigned short* __restrict__ VTg)
{
    __shared__ unsigned short T[64][72];
    const unsigned short* V = blockIdx.z ? Vg : Vl;
    unsigned short* Vt = blockIdx.z ? VTg : VTl;
    const int st = blockIdx.x, bh = blockIdx.y;
    const int b = bh >> 3, h = bh & 7;
    const int tid = threadIdx.x;
    {
        const int s = tid >> 2, d0 = (tid & 3) * 16;
        const unsigned short* src = V + ((size_t)(b * S_LEN + st * 64 + s) * DMODEL + h * 64 + d0);
        *(uint4*)&T[s][d0] = *(const uint4*)src;
        *(uint4*)&T[s][d0 + 8] = *(const uint4*)(src + 8);
    }
    __syncthreads();
    {
        const int d = tid >> 2, s0 = (tid & 3) * 16;
        unsigned short buf[16];
#pragma unroll
        for (int j = 0; j < 16; ++j) buf[j] = T[s0 + j][d];
        unsigned short* dst = Vt + ((size_t)(bh * 64 + d) * S_LEN + st * 64 + s0);
        *(uint4*)&dst[0] = *(const uint4*)&buf[0];
        *(uint4*)&dst[8] = *(const uint4*)&buf[8];
    }
}

// ---------------------------------------------------------------------------
// MFMA GEMM, global_load_lds staging, unpadded LDS + chunk-rotation swizzle.
// Templated on BN (64 or 128). BM=128, BK=64, 256 thr = 4 waves.
// Modes: 0 bias | 1 bias+pos | 2 relu | 3 gate blend (K=1024) |
//        5 merged QKV x2 paths (N=3072) | 6 dual Wo (blockIdx.z selects set)
// ---------------------------------------------------------------------------
template <int MODE, int BN>
__global__ __launch_bounds__(256) void gemm_mfma(
    const unsigned short* __restrict__ A, const unsigned short* __restrict__ A2,
    const unsigned short* __restrict__ Wt, const float* __restrict__ bias,
    const float* __restrict__ bias2, const float* __restrict__ pos,
    unsigned short* __restrict__ C, unsigned short* __restrict__ C2,
    int M, int N, int K)
{
    constexpr int UN = BN / 32;              // u-tiles per wave: 2 or 4
    __shared__ unsigned short As[128 * 64];
    __shared__ unsigned short Bs[BN * 64];
    const int tid = threadIdx.x;
    const int wave = tid >> 6, lane = tid & 63;
    const int lr = lane & 15, quad = lane >> 4;
    const int bm = blockIdx.x * 128, bn = blockIdx.y * BN;
    const int rm = (wave >> 1) * 64, rn = (wave & 1) * (BN / 2);
    const int Khalf = K >> 1;
    const int KA = (MODE == 3) ? Khalf : K;

    // dual-Wo path selection (block-uniform)
    const unsigned short* SA = A;
    const unsigned short* SW = Wt;
    const float* SBIAS = bias;
    unsigned short* SC = C;
    if constexpr (MODE == 6) {
        if (blockIdx.z) { SA = A2; SW = Wt + 512 * 512; SBIAS = bias2; SC = C2; }
    }

    // DMA lane geometry: 8 lanes/row, chunk rotated by row (conflict-free both ways)
    const int lrow = lane >> 3;
    const int gch = ((lane & 7) - lrow) & 7;
    const size_t laneA = (size_t)(bm + wave * 32 + lrow) * KA + gch * 8;
    const size_t laneB = (size_t)(bn + wave * (BN / 4) + lrow) * K + gch * 8;
    unsigned short* ldsA = As + wave * 2048;
    unsigned short* ldsB = Bs + wave * (BN * 16);

    f32x4 acc[4][UN];
#pragma unroll
    for (int t = 0; t < 4; ++t)
#pragma unroll
        for (int u = 0; u < UN; ++u) acc[t][u] = (f32x4){0.f, 0.f, 0.f, 0.f};

    const int sw0 = ((quad + lr) & 7) * 8;
    const int sw1 = ((quad + lr + 4) & 7) * 8;

    for (int k0 = 0; k0 < K; k0 += 64) {
        __syncthreads();                      // prev iteration's frag reads done
        const unsigned short* Ab; int kadj;
        if constexpr (MODE == 3) { Ab = (k0 < Khalf) ? A : A2; kadj = k0 & (Khalf - 1); }
        else { Ab = SA; kadj = k0; }
        const unsigned short* pa = Ab + laneA + kadj;
        glds16(pa,           ldsA,        lane);
        glds16(pa + 8 * KA,  ldsA + 512,  lane);
        glds16(pa + 16 * KA, ldsA + 1024, lane);
        glds16(pa + 24 * KA, ldsA + 1536, lane);
        const unsigned short* pb = SW + laneB + k0;
#pragma unroll
        for (int i = 0; i < UN; ++i)
            glds16(pb + i * 8 * K, ldsB + i * 512, lane);
        __syncthreads();                      // vmcnt(0) drain before reads

#pragma unroll
        for (int kc = 0; kc < 2; ++kc) {
            const int sw = kc ? sw1 : sw0;
            frag8 af[4], bf[UN];
#pragma unroll
            for (int t = 0; t < 4; ++t)
                af[t] = *(const frag8*)&As[(rm + t * 16 + lr) * 64 + sw];
#pragma unroll
            for (int u = 0; u < UN; ++u)
                bf[u] = *(const frag8*)&Bs[(rn + u * 16 + lr) * 64 + sw];
#pragma unroll
            for (int t = 0; t < 4; ++t)
#pragma unroll
                for (int u = 0; u < UN; ++u)
                    acc[t][u] = __builtin_amdgcn_mfma_f32_16x16x32_bf16(
                        af[t], bf[u], acc[t][u], 0, 0, 0);
        }
    }

    // ---- epilogue ----
#pragma unroll
    for (int t = 0; t < 4; ++t) {
#pragma unroll
        for (int i = 0; i < 4; ++i) {
            const int m = bm + rm + t * 16 + quad * 4 + i;
#pragma unroll
            for (int u = 0; u < UN; ++u) {
                const int n = bn + rn + u * 16 + lr;
                if constexpr (MODE == 5) {
                    const int mat = n >> 9;
                    const int nn = n & 511;
                    const float* bp = (mat < 3) ? (bias + (mat << 9))
                                                : (bias2 + ((mat - 3) << 9));
                    float v = acc[t][u][i] + bp[nn];
                    if (mat == 0 || mat == 3) v *= 0.18033688011112042f;  // 0.125*log2e
                    C[(size_t)mat * UAC + (size_t)m * DMODEL + nn] = f2bf(v);
                } else {
                    float v = acc[t][u][i] + SBIAS[n];
                    if constexpr (MODE == 1) v += pos[(size_t)(m & (S_LEN - 1)) * N + n];
                    if constexpr (MODE == 2) v = fmaxf(v, 0.0f);
                    if constexpr (MODE == 3) {
                        float g = tanhf(fmaxf(v, 0.0f));
                        float lo = bf2f(A[(size_t)m * Khalf + n]);
                        float go = bf2f(A2[(size_t)m * Khalf + n]);
                        v = g * lo + (1.0f - g) * go;
                    }
                    SC[(size_t)m * N + n] = f2bf(v);
                }
            }
        }
    }
}

// ---------------------------------------------------------------------------
// Unified MFMA flash attention, ONE launch for both paths.
// z = 0..7: z<4 -> GLOBAL (b=z, 32 K-tiles) dispatched FIRST so long blocks
// fill CUs at 6 blocks/CU (24 KB LDS); z>=4 -> LOCAL banded (b=z-4, 3 K-tiles)
// backfills. 64-row Q-tiles, single-buffer 2-barrier loop (measured best),
// transposed-S, max-free exp2 softmax, truncate-pack P (l from same values).
// ---------------------------------------------------------------------------
__global__ __launch_bounds__(256) void attn_mfma(
    const unsigned short* __restrict__ Ql, const unsigned short* __restrict__ Kl,
    const unsigned short* __restrict__ VTl, unsigned short* __restrict__ AOl,
    const unsigned short* __restrict__ Qg, const unsigned short* __restrict__ Kg,
    const unsigned short* __restrict__ VTg, unsigned short* __restrict__ AOg)
{
    __shared__ unsigned short Ks[64 * 64];
    __shared__ unsigned short Vts[64 * 64];
    __shared__ unsigned short Ps[64 * 64];
    const int qt = blockIdx.x, h = blockIdx.y;
    const int glob = blockIdx.z < 4;
    const int b = blockIdx.z & 3;
    const int masked = !glob;
    const unsigned short* Q  = glob ? Qg  : Ql;
    const unsigned short* Kv = glob ? Kg  : Kl;
    const unsigned short* Vt = glob ? VTg : VTl;
    unsigned short* O        = glob ? AOg : AOl;
    const int tid = threadIdx.x;
    const int wave = tid >> 6, lane = tid & 63;
    const int lr = lane & 15, quad = lane >> 4;

    {   // stage Q (wave-private rows) with chunk rotation
        const int q = tid >> 2, c8 = (tid & 3) * 2;
        const unsigned short* src = Q + ((size_t)(b * S_LEN + qt * 64 + q) * DMODEL + h * 64 + c8 * 8);
        *(uint4*)&Ps[q * 64 + (((c8 + q) & 7) * 8)] = *(const uint4*)src;
        *(uint4*)&Ps[q * 64 + (((c8 + 1 + q) & 7) * 8)] = *(const uint4*)(src + 8);
    }
    const int sw0 = ((quad + lr) & 7) * 8;
    const int sw1 = ((quad + lr + 4) & 7) * 8;
    const int prow = (wave * 16 + lr) * 64;
    frag8 qf[2];
    qf[0] = *(const frag8*)&Ps[prow + sw0];
    qf[1] = *(const frag8*)&Ps[prow + sw1];

    f32x4 oacc[4];
#pragma unroll
    for (int t = 0; t < 4; ++t) oacc[t] = (f32x4){0.f, 0.f, 0.f, 0.f};
    float l_r = 0.f;

    int kt0 = 0, kt1 = 31;
    if (masked) { kt0 = qt > 0 ? qt - 1 : 0; kt1 = qt < 31 ? qt + 1 : 31; }

    const int lrow = lane >> 3;
    const int gch = ((lane & 7) - lrow) & 7;
    const unsigned short* kp = Kv + ((size_t)(b * S_LEN + kt0 * 64 + wave * 16 + lrow) * DMODEL + h * 64 + gch * 8);
    const unsigned short* vp = Vt + ((size_t)((b * 8 + h) * 64 + wave * 16 + lrow) * S_LEN + kt0 * 64 + gch * 8);
    unsigned short* lk = Ks + wave * 1024;
    unsigned short* lv = Vts + wave * 1024;

    for (int kt = kt0; kt <= kt1; ++kt) {
        __syncthreads();
        glds16(kp, lk, lane);
        glds16(kp + 8 * DMODEL, lk + 512, lane);
        glds16(vp, lv, lane);
        glds16(vp + 8 * S_LEN, lv + 512, lane);
        kp += 64 * DMODEL; vp += 64;
        __syncthreads();

        f32x4 sacc[4];
#pragma unroll
        for (int t = 0; t < 4; ++t) sacc[t] = (f32x4){0.f, 0.f, 0.f, 0.f};
#pragma unroll
        for (int kc = 0; kc < 2; ++kc) {
            const int sw = kc ? sw1 : sw0;
#pragma unroll
            for (int t = 0; t < 4; ++t) {
                frag8 kf = *(const frag8*)&Ks[(t * 16 + lr) * 64 + sw];
                sacc[t] = __builtin_amdgcn_mfma_f32_16x16x32_bf16(kf, qf[kc], sacc[t], 0, 0, 0);
            }
        }

#pragma unroll
        for (int t = 0; t < 4; ++t) {
            float p0 = EXP2(sacc[t][0]);
            float p1 = EXP2(sacc[t][1]);
            float p2 = EXP2(sacc[t][2]);
            float p3 = EXP2(sacc[t][3]);
            if (masked) {
                const int qa = qt * 64 + wave * 16 + lr;
                const int ca = kt * 64 + t * 16 + quad * 4;
                int d0 = qa - ca;
                if (d0 > 32 || d0 < -32) p0 = 0.f;
                int d1 = qa - (ca + 1);
                if (d1 > 32 || d1 < -32) p1 = 0.f;
                int d2 = qa - (ca + 2);
                if (d2 > 32 || d2 < -32) p2 = 0.f;
                int d3 = qa - (ca + 3);
                if (d3 > 32 || d3 < -32) p3 = 0.f;
            }
            const unsigned u0 = __float_as_uint(p0) & 0xFFFF0000u;
            const unsigned u1 = __float_as_uint(p1) & 0xFFFF0000u;
            const unsigned u2 = __float_as_uint(p2) & 0xFFFF0000u;
            const unsigned u3 = __float_as_uint(p3) & 0xFFFF0000u;
            l_r += (__uint_as_float(u0) + __uint_as_float(u1)) +
                   (__uint_as_float(u2) + __uint_as_float(u3));
            uint2 pw;
            pw.x = __builtin_amdgcn_perm(u1, u0, 0x07060302);
            pw.y = __builtin_amdgcn_perm(u3, u2, 0x07060302);
            const int slot = ((2 * t + (quad >> 1) + lr) & 7) * 8 + (quad & 1) * 4;
            *(uint2*)&Ps[prow + slot] = pw;
        }
        // no barrier: Ps rows [16w,16w+16) written and read only by wave w

#pragma unroll
        for (int cc = 0; cc < 2; ++cc) {
            const int sw = cc ? sw1 : sw0;
            frag8 pa = *(const frag8*)&Ps[prow + sw];
#pragma unroll
            for (int t = 0; t < 4; ++t) {
                frag8 vf = *(const frag8*)&Vts[(t * 16 + lr) * 64 + sw];
                oacc[t] = __builtin_amdgcn_mfma_f32_16x16x32_bf16(pa, vf, oacc[t], 0, 0, 0);
            }
        }
    }

    l_r += __shfl_xor(l_r, 16);
    l_r += __shfl_xor(l_r, 32);
#pragma unroll
    for (int i = 0; i < 4; ++i) {
        const float inv = 1.0f / __shfl(l_r, quad * 4 + i);
        const int q = qt * 64 + wave * 16 + quad * 4 + i;
#pragma unroll
        for (int t = 0; t < 4; ++t)
            O[(size_t)(b * S_LEN + q) * DMODEL + h * 64 + t * 16 + lr] = f2bf(oacc[t][i] * inv);
    }
}

// ---------------------------------------------------------------------------
// LayerNorm (bf16 in/out, fp32 math): 256-thr blocks, one wave per row.
// ---------------------------------------------------------------------------
__device__ inline float wave_sum64(float v) {
#pragma unroll
    for (int off = 1; off < 64; off <<= 1) v += __shfl_xor(v, off);
    return v;
}

__global__ __launch_bounds__(256) void ln_res_kernel(
    const unsigned short* __restrict__ A, const unsigned short* __restrict__ Bb,
    const float* __restrict__ g, const float* __restrict__ be,
    unsigned short* __restrict__ out)
{
    const size_t row = blockIdx.x * 4 + (threadIdx.x >> 6);
    const int lane = threadIdx.x & 63;
    float x[8]; float s = 0.f;
#pragma unroll
    for (int k = 0; k < 8; ++k) {
        size_t idx = row * DMODEL + k * 64 + lane;
        x[k] = bf2f(A[idx]) + bf2f(Bb[idx]);
        s += x[k];
    }
    s = wave_sum64(s);
    float mean = s * (1.0f / DMODEL);
    float v = 0.f;
#pragma unroll
    for (int k = 0; k < 8; ++k) { float d = x[k] - mean; v += d * d; }
    v = wave_sum64(v) * (1.0f / DMODEL);
    float r = rsqrtf(v + 1e-5f);
#pragma unroll
    for (int k = 0; k < 8; ++k)
        out[row * DMODEL + k * 64 + lane] =
            f2bf((x[k] - mean) * r * g[k * 64 + lane] + be[k * 64 + lane]);
}

__global__ __launch_bounds__(256) void ln_double_kernel(
    const unsigned short* __restrict__ A, const unsigned short* __restrict__ Bb,
    const float* __restrict__ g2, const float* __restrict__ b2,
    const float* __restrict__ g3, const float* __restrict__ b3,
    unsigned short* __restrict__ out)
{
    const size_t row = blockIdx.x * 4 + (threadIdx.x >> 6);
    const int lane = threadIdx.x & 63;
    float x[8]; float s = 0.f;
#pragma unroll
    for (int k = 0; k < 8; ++k) {
        size_t idx = row * DMODEL + k * 64 + lane;
        x[k] = bf2f(A[idx]) + bf2f(Bb[idx]);
        s += x[k];
    }
    s = wave_sum64(s);
    float mean = s * (1.0f / DMODEL);
    float v = 0.f;
#pragma unroll
    for (int k = 0; k < 8; ++k) { float d = x[k] - mean; v += d * d; }
    v = wave_sum64(v) * (1.0f / DMODEL);
    float r = rsqrtf(v + 1e-5f);
    float t[8]; float s2 = 0.f;
#pragma unroll
    for (int k = 0; k < 8; ++k) {
        t[k] = (x[k] - mean) * r * g2[k * 64 + lane] + b2[k * 64 + lane];
        s2 += t[k];
    }
    s2 = wave_sum64(s2);
    float mean2 = s2 * (1.0f / DMODEL);
    float v2 = 0.f;
#pragma unroll
    for (int k = 0; k < 8; ++k) { float d = t[k] - mean2; v2 += d * d; }
    v2 = wave_sum64(v2) * (1.0f / DMODEL);
    float r2 = rsqrtf(v2 + 1e-5f);
#pragma unroll
    for (int k = 0; k < 8; ++k)
        out[row * DMODEL + k * 64 + lane] =
            f2bf((t[k] - mean2) * r2 * g3[k * 64 + lane] + b3[k * 64 + lane]);
}

// ---------------------------------------------------------------------------
// Mean-pool over S: per-chunk partials (no atomics, no memset) + final
// reduce-and-project kernel.
// ---------------------------------------------------------------------------
__global__ __launch_bounds__(256) void pool_kernel(
    const unsigned short* __restrict__ h2, float* __restrict__ partials)
{
    const int b = blockIdx.x >> 4;
    const int chunk = blockIdx.x & 15;
    const int tid = threadIdx.x;
    float s0 = 0.f, s1 = 0.f;
    size_t base = (size_t)(b * S_LEN + chunk * 128) * DMODEL;
    for (int r = 0; r < 128; ++r) {
        s0 += bf2f(h2[base + (size_t)r * DMODEL + tid]);
        s1 += bf2f(h2[base + (size_t)r * DMODEL + 256 + tid]);
    }
    partials[(size_t)(b * 16 + chunk) * DMODEL + tid] = s0;
    partials[(size_t)(b * 16 + chunk) * DMODEL + 256 + tid] = s1;
}

__global__ __launch_bounds__(128) void out_kernel(
    const float* __restrict__ partials, const float* __restrict__ w,
    const float* __restrict__ bias, float* __restrict__ out)
{
    __shared__ float pooled[DMODEL];
    const int b = blockIdx.x;
    const int o = threadIdx.x;
#pragma unroll
    for (int j = 0; j < 4; ++j) {
        const int d = j * 128 + o;
        float s = 0.f;
#pragma unroll
        for (int c = 0; c < 16; ++c)
            s += partials[(size_t)(b * 16 + c) * DMODEL + d];
        pooled[d] = s;
    }
    __syncthreads();
    float acc = 0.f;
    for (int d = 0; d < DMODEL; ++d)
        acc += pooled[d] * w[d * 128 + o];
    out[b * 128 + o] = acc * (1.0f / S_LEN) + bias[o];
}

// ---------------------------------------------------------------------------
extern "C" void kernel_launch(void* const* d_in, const int* in_sizes, int n_in,
                              void* d_out, int out_size, void* d_ws, size_t ws_size,
                              hipStream_t stream)
{
    const float* x      = (const float*)d_in[0];
    const float* pos    = (const float*)d_in[1];
    const float* win_w  = (const float*)d_in[2];
    const float* win_b  = (const float*)d_in[3];
    const float* l_wqkv = (const float*)d_in[4];
    const float* l_bqkv = (const float*)d_in[5];
    const float* l_wo   = (const float*)d_in[6];
    const float* l_bo   = (const float*)d_in[7];
    const float* g_wqkv = (const float*)d_in[8];
    const float* g_bqkv = (const float*)d_in[9];
    const float* g_wo   = (const float*)d_in[10];
    const float* g_bo   = (const float*)d_in[11];
    const float* gate_w = (const float*)d_in[12];
    const float* gate_b = (const float*)d_in[13];
    const float* ffn_w1 = (const float*)d_in[14];
    const float* ffn_b1 = (const float*)d_in[15];
    const float* ffn_w2 = (const float*)d_in[16];
    const float* ffn_b2 = (const float*)d_in[17];
    const float* n1_g   = (const float*)d_in[18];
    const float* n1_b   = (const float*)d_in[19];
    const float* n2_g   = (const float*)d_in[20];
    const float* n2_b   = (const float*)d_in[21];
    const float* n3_g   = (const float*)d_in[22];
    const float* n3_b   = (const float*)d_in[23];
    const float* out_w  = (const float*)d_in[24];
    const float* out_b  = (const float*)d_in[25];
    float* out = (float*)d_out;

    unsigned short* ws16 = (unsigned short*)d_ws;
    const size_t UA = (size_t)UAC;
    // units 0..7 (8 MiB each):
    unsigned short* H    = ws16 + 0 * UA;
    unsigned short* QKV  = ws16 + 1 * UA;   // units 1..6: Ql,Kl,Vl,Qg,Kg,Vg
    unsigned short* Ql   = ws16 + 1 * UA;
    unsigned short* Kl   = ws16 + 2 * UA;
    unsigned short* Vl   = ws16 + 3 * UA;
    unsigned short* Qg   = ws16 + 4 * UA;
    unsigned short* Kg   = ws16 + 5 * UA;
    unsigned short* Vg   = ws16 + 6 * UA;
    unsigned short* VTl  = ws16 + 7 * UA;   // transposed V local (B*H,64,S)
    unsigned short* AOl    = Vl;            // Vl dead after vtrans2
    unsigned short* LO     = Kl;            // Kl dead after attn
    unsigned short* GO     = Qg;            // Qg dead after attn
    unsigned short* FUSED  = Kg;            // Kg dead after attn
    unsigned short* H1     = Vg;            // Vg dead after vtrans2
    unsigned short* FFNMID = Vl;            // units 3..4 (AOl, GO dead post-gate)
    unsigned short* FFNOUT = Ql;            // Ql dead after attn
    unsigned short* H2     = Kl;            // LO dead after gate

    // transposed bf16 weights + pre-cast x
    unsigned short* wt = ws16 + 8 * UA;
    unsigned short* win_t  = wt;                      // 512 x 256
    unsigned short* lqkv_t = win_t  + 131072;         // 3 x (512 x 512)
    unsigned short* gqkv_t = lqkv_t + 786432;         // 3 x (512 x 512)
    unsigned short* lwo_t  = gqkv_t + 786432;
    unsigned short* gwo_t  = lwo_t  + 262144;
    unsigned short* gate_t = gwo_t  + 262144;         // 512 x 1024
    unsigned short* ffn1_t = gate_t + 524288;         // 1024 x 512
    unsigned short* ffn2_t = ffn1_t + 524288;         // 512 x 1024
    unsigned short* xb     = ffn2_t + 524288;         // 8192 x 256 bf16
    // spare region (proven ws >= 91.8 MB by R9 layout)
    unsigned short* VTg    = xb + 2097152;            // 8 MB: transposed V global
    unsigned short* AOg    = VTg + UA;                // 8 MB: global attn out
    float* PARTIALS = (float*)(void*)(AOg + UA);      // 64 x 512 f32 = 128 KB

    WTab tab;
    tab.s[0]  = {win_w,             win_t,             256,  512,    0};
    tab.s[1]  = {l_wqkv + 0*262144, lqkv_t + 0*262144, 512,  512,  128};
    tab.s[2]  = {l_wqkv + 1*262144, lqkv_t + 1*262144, 512,  512,  384};
    tab.s[3]  = {l_wqkv + 2*262144, lqkv_t + 2*262144, 512,  512,  640};
    tab.s[4]  = {g_wqkv + 0*262144, gqkv_t + 0*262144, 512,  512,  896};
    tab.s[5]  = {g_wqkv + 1*262144, gqkv_t + 1*262144, 512,  512, 1152};
    tab.s[6]  = {g_wqkv + 2*262144, gqkv_t + 2*262144, 512,  512, 1408};
    tab.s[7]  = {l_wo,              lwo_t,             512,  512, 1664};
    tab.s[8]  = {g_wo,              gwo_t,             512,  512, 1920};
    tab.s[9]  = {gate_w,            gate_t,            1024, 512, 2176};
    tab.s[10] = {ffn_w1,            ffn1_t,            512, 1024, 2688};
    tab.s[11] = {ffn_w2,            ffn2_t,            1024, 512, 3200};
    tab.s[12] = {x,                 xb,                0,    0,   3712};   // plain cast

    dim3 blk(256);
    wcast_all<<<dim3(4736), blk, 0, stream>>>(tab);

    dim3 gD(M_ROWS / 128, 512 / 64);        // 64 x 8   (BN=64)
    dim3 gW(M_ROWS / 128, 512 / 64, 2);     // dual Wo
    dim3 gQ(M_ROWS / 128, 3072 / 128);      // 64 x 24  (BN=128, merged QKV x2)
    dim3 gF(M_ROWS / 128, 1024 / 128);      // 64 x 8   (BN=128, FFN1)
    dim3 gAT(S_LEN / 64, NHEAD, 2*BATCH);   // unified attn: 32 x 8 x 8 (globals z<4)
    dim3 gV(S_LEN / 64, BATCH * NHEAD, 2);  // dual vtrans

    // h = x @ win_w + win_b + pos
    gemm_mfma<1, 64><<<gD, blk, 0, stream>>>(xb, nullptr, win_t, win_b, nullptr, pos, H, nullptr, M_ROWS, 512, 256);

    // merged QKV for both paths (Q mats pre-scaled by 0.125*log2e)
    gemm_mfma<5, 128><<<gQ, blk, 0, stream>>>(H, nullptr, lqkv_t, l_bqkv, g_bqkv, nullptr, QKV, nullptr, M_ROWS, 3072, 512);

    // dual V transpose (both paths at once)
    vtrans2_kernel<<<gV, blk, 0, stream>>>(Vl, Vg, VTl, VTg);

    // unified attention: global (z<4, long) + local (z>=4, short backfill)
    attn_mfma<<<gAT, blk, 0, stream>>>(Ql, Kl, VTl, AOl, Qg, Kg, VTg, AOg);

    // dual Wo: z=0 local (AOl@lwo -> LO), z=1 global (AOg@gwo -> GO)
    gemm_mfma<6, 64><<<gW, blk, 0, stream>>>(AOl, AOg, lwo_t, l_bo, g_bo, nullptr, LO, GO, M_ROWS, 512, 512);

    // gate + fuse
    gemm_mfma<3, 64><<<gD, blk, 0, stream>>>(LO, GO, gate_t, gate_b, nullptr, nullptr, FUSED, nullptr, M_ROWS, 512, 1024);

    // h1 = LN(h + fused)
    ln_res_kernel<<<M_ROWS / 4, blk, 0, stream>>>(H, FUSED, n1_g, n1_b, H1);

    // FFN
    gemm_mfma<2, 128><<<gF, blk, 0, stream>>>(H1, nullptr, ffn1_t, ffn_b1, nullptr, nullptr, FFNMID, nullptr, M_ROWS, 1024, 512);
    gemm_mfma<0, 64><<<gD, blk, 0, stream>>>(FFNMID, nullptr, ffn2_t, ffn_b2, nullptr, nullptr, FFNOUT, nullptr, M_ROWS, 512, 1024);

    // h2 = LN(LN(h1 + ffn, n2), n3)
    ln_double_kernel<<<M_ROWS / 4, blk, 0, stream>>>(H1, FFNOUT, n2_g, n2_b, n3_g, n3_b, H2);

    // pool partials + final reduce/projection (no atomics, no memset)
    pool_kernel<<<dim3(BATCH * 16), blk, 0, stream>>>(H2, PARTIALS);
    out_kernel<<<dim3(BATCH), dim3(128), 0, stream>>>(PARTIALS, out_w, out_b, out);
}